// Round 2
// baseline (708.866 us; speedup 1.0000x reference)
//
#include <hip/hip_runtime.h>
#include <hip/hip_bf16.h>

#define N_NODES 50000
#define N_EDGES 1600000
#define IN_DIM  256
#define OUT_DIM 128
#define T_STEPS 8

typedef __attribute__((ext_vector_type(8))) short bf16x8;
typedef __attribute__((ext_vector_type(4))) float f32x4;

// ---- ws layout (bytes) ----
// hs    : bf16 [N*128]    @ 0           (12,800,000)  hs[i] = bf16(dinv[i]*h[i])
// Wt_hi : bf16 [128*256]  @ 12,800,000  (65,536)
// Wt_lo : bf16 [128*256]  @ 12,865,536  (65,536)
// cnt   : int  [N]        @ 12,931,072  (200,000)   (memset to 0)
// fill  : int  [N]        @ 13,131,072  (200,000)   (init = offs by k_scanC)
// offs  : int  [N]        @ 13,331,072  (200,000)
// dinv  : f32  [N]        @ 13,531,072  (200,000)
// part  : int  [64]       @ 13,731,072  (256)
// csr   : u16  [E]        @ 13,731,328  (3,200,000)   <-- ushort (ids < 65536)

__device__ inline unsigned short bf_hi_trunc(float x) {
    return (unsigned short)(__float_as_uint(x) >> 16);
}
__device__ inline float bf_to_f(unsigned short u) {
    return __uint_as_float((unsigned)u << 16);
}
__device__ inline unsigned short f2bf_rne(float a) {
    __hip_bfloat16 t = __float2bfloat16(a);
    return *(unsigned short*)&t;
}
__device__ inline float bf_lo(unsigned p) { return __uint_as_float(p << 16); }
__device__ inline float bf_hi(unsigned p) { return __uint_as_float(p & 0xffff0000u); }

// W split (hi/lo bf16, transposed) + edge-dst histogram (int4 edge loads).
__global__ __launch_bounds__(256) void
k_prep_count(const float* __restrict__ W,
             unsigned short* __restrict__ Wt_hi,
             unsigned short* __restrict__ Wt_lo,
             const int* __restrict__ edge, int* __restrict__ cnt) {
    int idx = blockIdx.x * 256 + threadIdx.x;   // 204800 threads
    const int4* dst4 = (const int4*)(edge + N_EDGES);
    for (int e = idx; e < N_EDGES / 4; e += 800 * 256) {
        int4 d = dst4[e];
        atomicAdd(&cnt[d.x], 1);
        atomicAdd(&cnt[d.y], 1);
        atomicAdd(&cnt[d.z], 1);
        atomicAdd(&cnt[d.w], 1);
    }
    if (idx < 32768) {
        int n = idx >> 8;      // out dim
        int k = idx & 255;     // in dim
        float w = W[k * OUT_DIM + n];
        unsigned short hi = bf_hi_trunc(w);
        Wt_hi[idx] = hi;
        Wt_lo[idx] = f2bf_rne(w - bf_to_f(hi));
    }
}

// ---- 3-phase exclusive scan of cnt[50000] (12500 int4 per phase-block) ----
__global__ __launch_bounds__(256) void
k_scanA(const int* __restrict__ cnt, int* __restrict__ part) {
    int t = threadIdx.x;
    int i4 = blockIdx.x * 256 + t;
    int4 v = make_int4(0, 0, 0, 0);
    if (i4 < 12500) v = ((const int4*)cnt)[i4];
    int s = v.x + v.y + v.z + v.w;
    __shared__ int sd[256];
    sd[t] = s; __syncthreads();
    for (int o = 128; o > 0; o >>= 1) {
        if (t < o) sd[t] += sd[t + o];
        __syncthreads();
    }
    if (t == 0) part[blockIdx.x] = sd[0];
}

__global__ void k_scanB(int* __restrict__ part) {   // 1 wave
    int l = threadIdx.x;
    int v = (l < 49) ? part[l] : 0;
    int orig = v;
    for (int o = 1; o < 64; o <<= 1) {
        int u = __shfl_up(v, o);
        if (l >= o) v += u;
    }
    if (l < 49) part[l] = v - orig;   // exclusive
}

__global__ __launch_bounds__(256) void
k_scanC(const int* __restrict__ cnt, const int* __restrict__ part,
        int* __restrict__ offs, int* __restrict__ fill,
        float* __restrict__ dinv) {
    int t = threadIdx.x;
    int i4 = blockIdx.x * 256 + t;
    int4 v = make_int4(0, 0, 0, 0);
    if (i4 < 12500) v = ((const int4*)cnt)[i4];
    int s = v.x + v.y + v.z + v.w;
    __shared__ int sd[256];
    sd[t] = s; __syncthreads();
    for (int o = 1; o < 256; o <<= 1) {           // inclusive Hillis-Steele
        int u = (t >= o) ? sd[t - o] : 0;
        __syncthreads();
        sd[t] += u;
        __syncthreads();
    }
    if (i4 < 12500) {
        int base = part[blockIdx.x] + sd[t] - s;  // exclusive
        int4 o4;
        o4.x = base;
        o4.y = o4.x + v.x;
        o4.z = o4.y + v.y;
        o4.w = o4.z + v.z;
        ((int4*)offs)[i4] = o4;
        ((int4*)fill)[i4] = o4;                   // k_fill's running cursor
        float4 d4;
        d4.x = rsqrtf((float)(v.x + 1));
        d4.y = rsqrtf((float)(v.y + 1));
        d4.z = rsqrtf((float)(v.z + 1));
        d4.w = rsqrtf((float)(v.w + 1));
        ((float4*)dinv)[i4] = d4;
    }
}

// GEMM x@W with split-bf16, epilogue writes hs = bf16(dinv[row] * acc).
__global__ __launch_bounds__(256) void
k_gemm(const float* __restrict__ x,
       const unsigned short* __restrict__ Wt_hi,
       const unsigned short* __restrict__ Wt_lo,
       const float* __restrict__ dinv,
       unsigned short* __restrict__ hs) {
    int wave = blockIdx.x * 4 + (threadIdx.x >> 6);
    if (wave >= N_NODES / 16) return;           // 3125 M-tiles of 16 rows
    int lane = threadIdx.x & 63;
    int quad = lane >> 4;
    int r16  = lane & 15;
    int m0 = wave * 16;

    f32x4 acc[8];
#pragma unroll
    for (int nt = 0; nt < 8; ++nt) acc[nt] = (f32x4){0.f, 0.f, 0.f, 0.f};

#pragma unroll
    for (int kt = 0; kt < 8; ++kt) {
        int k0 = kt * 32 + quad * 8;
        const float* xp = x + (size_t)(m0 + r16) * IN_DIM + k0;
        float4 v0 = *(const float4*)xp;
        float4 v1 = *(const float4*)(xp + 4);
        float vv[8] = {v0.x, v0.y, v0.z, v0.w, v1.x, v1.y, v1.z, v1.w};
        union { bf16x8 v; unsigned short u[8]; } ahi, alo;
#pragma unroll
        for (int j = 0; j < 8; ++j) {
            unsigned short hi = bf_hi_trunc(vv[j]);
            ahi.u[j] = hi;
            alo.u[j] = f2bf_rne(vv[j] - bf_to_f(hi));
        }
#pragma unroll
        for (int nt = 0; nt < 8; ++nt) {
            size_t woff = (size_t)(nt * 16 + r16) * IN_DIM + k0;
            bf16x8 bhi = *(const bf16x8*)(Wt_hi + woff);
            bf16x8 blo = *(const bf16x8*)(Wt_lo + woff);
            acc[nt] = __builtin_amdgcn_mfma_f32_16x16x32_bf16(ahi.v, bhi, acc[nt], 0, 0, 0);
            acc[nt] = __builtin_amdgcn_mfma_f32_16x16x32_bf16(alo.v, bhi, acc[nt], 0, 0, 0);
            acc[nt] = __builtin_amdgcn_mfma_f32_16x16x32_bf16(ahi.v, blo, acc[nt], 0, 0, 0);
        }
    }
    float dr[4];
#pragma unroll
    for (int r = 0; r < 4; ++r) dr[r] = dinv[m0 + quad * 4 + r];
#pragma unroll
    for (int nt = 0; nt < 8; ++nt) {
#pragma unroll
        for (int r = 0; r < 4; ++r) {
            int row = m0 + quad * 4 + r;
            int col = nt * 16 + r16;
            hs[(size_t)row * OUT_DIM + col] = f2bf_rne(acc[nt][r] * dr[r]);
        }
    }
}

__global__ __launch_bounds__(256) void
k_fill(const int* __restrict__ edge, int* __restrict__ fill,
       unsigned short* __restrict__ csr) {
    int e4 = blockIdx.x * 256 + threadIdx.x;    // 400000 int4 groups
    if (e4 < N_EDGES / 4) {
        int4 s = ((const int4*)edge)[e4];
        int4 d = ((const int4*)(edge + N_EDGES))[e4];
        int p;
        p = atomicAdd(&fill[d.x], 1); csr[p] = (unsigned short)s.x;
        p = atomicAdd(&fill[d.y], 1); csr[p] = (unsigned short)s.y;
        p = atomicAdd(&fill[d.z], 1); csr[p] = (unsigned short)s.z;
        p = atomicAdd(&fill[d.w], 1); csr[p] = (unsigned short)s.w;
    }
}

// One wave per node. Lanes 0-31 process even-indexed edges, lanes 32-63
// odd-indexed edges; each lane gathers uint2 (4 dims of bf16) so one VMEM
// instruction covers TWO edges' 256B rows. csr consumed as uniform dwords
// (one dword = both halves' src ids). Halves merged via shfl(lane^32).
__global__ __launch_bounds__(256) void
k_agg_snn(const unsigned short* __restrict__ hs,
          const int* __restrict__ offs, const int* __restrict__ cnt,
          const float* __restrict__ dinv,
          const unsigned short* __restrict__ csr,
          float* __restrict__ out) {
    int node = blockIdx.x * 4 + (threadIdx.x >> 6);   // one wave per node
    int lane = threadIdx.x & 63;
    bool hi  = (lane >= 32);
    int  loff = (lane & 31) * 8;                      // byte offset in 256B row
    const char* hsb = (const char*)hs;

    // self-loop term: both halves load the same 8B (coalesced); only the
    // high half keeps it so it is counted once.
    uint2 qs = *(const uint2*)(hsb + (size_t)node * 256 + loff);
    float a0 = hi ? bf_lo(qs.x) : 0.f;
    float a1 = hi ? bf_hi(qs.x) : 0.f;
    float a2 = hi ? bf_lo(qs.y) : 0.f;
    float a3 = hi ? bf_hi(qs.y) : 0.f;

    int beg = __builtin_amdgcn_readfirstlane(offs[node]);
    int end = __builtin_amdgcn_readfirstlane(offs[node] + cnt[node]);

    int j = beg;
    if (j & 1) {                                      // align to even element
        unsigned s = csr[j];
        if (!hi) {
            uint2 q = *(const uint2*)(hsb + (size_t)s * 256 + loff);
            a0 += bf_lo(q.x); a1 += bf_hi(q.x);
            a2 += bf_lo(q.y); a3 += bf_hi(q.y);
        }
        ++j;
    }
    int nd = (end - j) >> 1;                          // edge pairs
    const unsigned* cw = (const unsigned*)(csr + j);  // dword-aligned now
    int k = 0;
    for (; k + 8 <= nd; k += 8) {                     // 16 edges in flight
        unsigned d[8];
#pragma unroll
        for (int q = 0; q < 8; ++q) d[q] = cw[k + q];
        uint2 g[8];
#pragma unroll
        for (int q = 0; q < 8; ++q) {
            unsigned s = hi ? (d[q] >> 16) : (d[q] & 0xffffu);
            g[q] = *(const uint2*)(hsb + (size_t)s * 256 + loff);
        }
#pragma unroll
        for (int q = 0; q < 8; ++q) {
            a0 += bf_lo(g[q].x); a1 += bf_hi(g[q].x);
            a2 += bf_lo(g[q].y); a3 += bf_hi(g[q].y);
        }
    }
    for (; k < nd; ++k) {
        unsigned d = cw[k];
        unsigned s = hi ? (d >> 16) : (d & 0xffffu);
        uint2 q = *(const uint2*)(hsb + (size_t)s * 256 + loff);
        a0 += bf_lo(q.x); a1 += bf_hi(q.x);
        a2 += bf_lo(q.y); a3 += bf_hi(q.y);
    }
    int jt = j + 2 * nd;
    if (jt < end) {                                   // odd tail edge
        unsigned s = csr[jt];
        if (!hi) {
            uint2 q = *(const uint2*)(hsb + (size_t)s * 256 + loff);
            a0 += bf_lo(q.x); a1 += bf_hi(q.x);
            a2 += bf_lo(q.y); a3 += bf_hi(q.y);
        }
    }

    // merge the two half-wave partial sums (same dims, different edges)
    a0 += __shfl(a0, lane ^ 32);
    a1 += __shfl(a1, lane ^ 32);
    a2 += __shfl(a2, lane ^ 32);
    a3 += __shfl(a3, lane ^ 32);

    float di = dinv[node];
    float u0 = a0 * di * 0.1f, u1 = a1 * di * 0.1f;   // STEP_SIZE
    float u2 = a2 * di * 0.1f, u3 = a3 * di * 0.1f;
    float z0 = 0.f, z1 = 0.f, z2 = 0.f, z3 = 0.f;

    const size_t plane = (size_t)N_NODES * 128;       // floats per t-plane
    // low half stores the o-plane, high half the z-plane (full-wave 16B/lane)
    size_t base = (size_t)node * 128 + (size_t)(lane & 31) * 4
                + (hi ? (size_t)T_STEPS * plane : 0);
#pragma unroll
    for (int t = 0; t < T_STEPS; ++t) {
        float H0 = z0 + (u0 - z0) * 0.5f;             // TAU = 2
        float H1 = z1 + (u1 - z1) * 0.5f;
        float H2 = z2 + (u2 - z2) * 0.5f;
        float H3 = z3 + (u3 - z3) * 0.5f;
        float o0 = (H0 >= 1.0f) ? 1.0f : 0.0f;        // V_THRESHOLD = 1
        float o1 = (H1 >= 1.0f) ? 1.0f : 0.0f;
        float o2 = (H2 >= 1.0f) ? 1.0f : 0.0f;
        float o3 = (H3 >= 1.0f) ? 1.0f : 0.0f;
        z0 = H0 - o0; z1 = H1 - o1; z2 = H2 - o2; z3 = H3 - o3;
        f32x4 v = {hi ? z0 : o0, hi ? z1 : o1,
                   hi ? z2 : o2, hi ? z3 : o3};
        // streaming stores: don't evict the hs gather table from L2/L3
        __builtin_nontemporal_store(v, (f32x4*)(out + base + (size_t)t * plane));
    }
}

extern "C" void kernel_launch(void* const* d_in, const int* in_sizes, int n_in,
                              void* d_out, int out_size, void* d_ws, size_t ws_size,
                              hipStream_t stream) {
    const float* x  = (const float*)d_in[0];
    const float* W  = (const float*)d_in[1];
    const int*   ei = (const int*)d_in[2];
    float* out = (float*)d_out;

    char* ws = (char*)d_ws;
    unsigned short* hs    = (unsigned short*)(ws + 0);
    unsigned short* Wt_hi = (unsigned short*)(ws + 12800000);
    unsigned short* Wt_lo = (unsigned short*)(ws + 12865536);
    int*            cnt   = (int*)(ws + 12931072);
    int*            fill  = (int*)(ws + 13131072);
    int*            offs  = (int*)(ws + 13331072);
    float*          dinv  = (float*)(ws + 13531072);
    int*            part  = (int*)(ws + 13731072);
    unsigned short* csr   = (unsigned short*)(ws + 13731328);

    hipMemsetAsync(cnt, 0, 200000, stream);

    k_prep_count<<<800, 256, 0, stream>>>(W, Wt_hi, Wt_lo, ei, cnt);
    k_scanA<<<49, 256, 0, stream>>>(cnt, part);
    k_scanB<<<1, 64, 0, stream>>>(part);
    k_scanC<<<49, 256, 0, stream>>>(cnt, part, offs, fill, dinv);
    k_gemm<<<782, 256, 0, stream>>>(x, Wt_hi, Wt_lo, dinv, hs);
    k_fill<<<1563, 256, 0, stream>>>(ei, fill, csr);
    k_agg_snn<<<12500, 256, 0, stream>>>(hs, offs, cnt, dinv, csr, out);
}

// Round 3
// 694.338 us; speedup vs baseline: 1.0209x; 1.0209x over previous
//
#include <hip/hip_runtime.h>
#include <hip/hip_bf16.h>

#define N_NODES 50000
#define N_EDGES 1600000
#define IN_DIM  256
#define OUT_DIM 128
#define T_STEPS 8
#define NREP    8          // counter replicas (≈ one per XCD)

typedef __attribute__((ext_vector_type(8))) short bf16x8;
typedef __attribute__((ext_vector_type(4))) float f32x4;

// ---- ws layout (bytes) ----
// hs     : bf16 [N*128]     @ 0           (12,800,000)
// Wt_hi  : bf16 [128*256]   @ 12,800,000  (65,536)
// Wt_lo  : bf16 [128*256]   @ 12,865,536  (65,536)
// cnt_x  : int  [8][N]      @ 12,931,072  (1,600,000)  (memset to 0)
// fill_x : int  [8][N]      @ 14,531,072  (1,600,000)  (init by k_scanC: segment cursors)
// offs   : int  [N]         @ 16,131,072  (200,000)    (node CSR base)
// deg    : int  [N]         @ 16,331,072  (200,000)    (node in-degree)
// dinv   : f32  [N]         @ 16,531,072  (200,000)
// part   : int  [64]        @ 16,731,072  (256)
// csr    : u16  [E]         @ 16,731,328  (3,200,000)

__device__ inline unsigned short bf_hi_trunc(float x) {
    return (unsigned short)(__float_as_uint(x) >> 16);
}
__device__ inline float bf_to_f(unsigned short u) {
    return __uint_as_float((unsigned)u << 16);
}
__device__ inline unsigned short f2bf_rne(float a) {
    __hip_bfloat16 t = __float2bfloat16(a);
    return *(unsigned short*)&t;
}
__device__ inline float bf_lo(unsigned p) { return __uint_as_float(p << 16); }
__device__ inline float bf_hi(unsigned p) { return __uint_as_float(p & 0xffff0000u); }

// Histogram into replica (blockIdx&7) -> atomic lines stay XCD-local under
// round-robin dispatch. Grid MUST match k_fill exactly (same edge->replica map).
// Also folds the W hi/lo split (blocks 0..127).
__global__ __launch_bounds__(256) void
k_count(const float* __restrict__ W,
        unsigned short* __restrict__ Wt_hi,
        unsigned short* __restrict__ Wt_lo,
        const int* __restrict__ edge, int* __restrict__ cnt_x) {
    int idx = blockIdx.x * 256 + threadIdx.x;
    int* my = cnt_x + (blockIdx.x & (NREP - 1)) * N_NODES;
    if (idx < N_EDGES / 4) {
        int4 d = ((const int4*)(edge + N_EDGES))[idx];
        atomicAdd(&my[d.x], 1);
        atomicAdd(&my[d.y], 1);
        atomicAdd(&my[d.z], 1);
        atomicAdd(&my[d.w], 1);
    }
    if (idx < 32768) {
        int n = idx >> 8;      // out dim
        int k = idx & 255;     // in dim
        float w = W[k * OUT_DIM + n];
        unsigned short hi = bf_hi_trunc(w);
        Wt_hi[idx] = hi;
        Wt_lo[idx] = f2bf_rne(w - bf_to_f(hi));
    }
}

// ---- 3-phase exclusive scan over per-node totals (sum of 8 replicas) ----
__global__ __launch_bounds__(256) void
k_scanA(const int* __restrict__ cnt_x, int* __restrict__ part) {
    int t = threadIdx.x;
    int i4 = blockIdx.x * 256 + t;
    int4 v = make_int4(0, 0, 0, 0);
    if (i4 < 12500) {
#pragma unroll
        for (int r = 0; r < NREP; ++r) {
            int4 c = ((const int4*)(cnt_x + r * N_NODES))[i4];
            v.x += c.x; v.y += c.y; v.z += c.z; v.w += c.w;
        }
    }
    int s = v.x + v.y + v.z + v.w;
    __shared__ int sd[256];
    sd[t] = s; __syncthreads();
    for (int o = 128; o > 0; o >>= 1) {
        if (t < o) sd[t] += sd[t + o];
        __syncthreads();
    }
    if (t == 0) part[blockIdx.x] = sd[0];
}

__global__ void k_scanB(int* __restrict__ part) {   // 1 wave
    int l = threadIdx.x;
    int v = (l < 49) ? part[l] : 0;
    int orig = v;
    for (int o = 1; o < 64; o <<= 1) {
        int u = __shfl_up(v, o);
        if (l >= o) v += u;
    }
    if (l < 49) part[l] = v - orig;   // exclusive
}

// Emits: offs (node base), deg, dinv, and the 8 per-node segment cursors
// fill_x[r][n] = offs[n] + sum_{r'<r} cnt_x[r'][n]  (node-major segments).
__global__ __launch_bounds__(256) void
k_scanC(const int* __restrict__ cnt_x, const int* __restrict__ part,
        int* __restrict__ offs, int* __restrict__ deg,
        int* __restrict__ fill_x, float* __restrict__ dinv) {
    int t = threadIdx.x;
    int i4 = blockIdx.x * 256 + t;
    int4 vr[NREP];
    int4 tot = make_int4(0, 0, 0, 0);
    if (i4 < 12500) {
#pragma unroll
        for (int r = 0; r < NREP; ++r) {
            vr[r] = ((const int4*)(cnt_x + r * N_NODES))[i4];
            tot.x += vr[r].x; tot.y += vr[r].y;
            tot.z += vr[r].z; tot.w += vr[r].w;
        }
    } else {
#pragma unroll
        for (int r = 0; r < NREP; ++r) vr[r] = make_int4(0, 0, 0, 0);
    }
    int s = tot.x + tot.y + tot.z + tot.w;
    __shared__ int sd[256];
    sd[t] = s; __syncthreads();
    for (int o = 1; o < 256; o <<= 1) {           // inclusive Hillis-Steele
        int u = (t >= o) ? sd[t - o] : 0;
        __syncthreads();
        sd[t] += u;
        __syncthreads();
    }
    if (i4 < 12500) {
        int base = part[blockIdx.x] + sd[t] - s;  // exclusive
        int4 o4;
        o4.x = base;
        o4.y = o4.x + tot.x;
        o4.z = o4.y + tot.y;
        o4.w = o4.z + tot.z;
        ((int4*)offs)[i4] = o4;
        ((int4*)deg)[i4]  = tot;
        float4 d4;
        d4.x = rsqrtf((float)(tot.x + 1));
        d4.y = rsqrtf((float)(tot.y + 1));
        d4.z = rsqrtf((float)(tot.z + 1));
        d4.w = rsqrtf((float)(tot.w + 1));
        ((float4*)dinv)[i4] = d4;
        int c0 = o4.x, c1 = o4.y, c2 = o4.z, c3 = o4.w;
#pragma unroll
        for (int r = 0; r < NREP; ++r) {
            int4 c4 = make_int4(c0, c1, c2, c3);
            ((int4*)(fill_x + r * N_NODES))[i4] = c4;
            c0 += vr[r].x; c1 += vr[r].y; c2 += vr[r].z; c3 += vr[r].w;
        }
    }
}

// GEMM x@W with split-bf16, epilogue writes hs = bf16(dinv[row] * acc).
__global__ __launch_bounds__(256) void
k_gemm(const float* __restrict__ x,
       const unsigned short* __restrict__ Wt_hi,
       const unsigned short* __restrict__ Wt_lo,
       const float* __restrict__ dinv,
       unsigned short* __restrict__ hs) {
    int wave = blockIdx.x * 4 + (threadIdx.x >> 6);
    if (wave >= N_NODES / 16) return;           // 3125 M-tiles of 16 rows
    int lane = threadIdx.x & 63;
    int quad = lane >> 4;
    int r16  = lane & 15;
    int m0 = wave * 16;

    f32x4 acc[8];
#pragma unroll
    for (int nt = 0; nt < 8; ++nt) acc[nt] = (f32x4){0.f, 0.f, 0.f, 0.f};

#pragma unroll
    for (int kt = 0; kt < 8; ++kt) {
        int k0 = kt * 32 + quad * 8;
        const float* xp = x + (size_t)(m0 + r16) * IN_DIM + k0;
        float4 v0 = *(const float4*)xp;
        float4 v1 = *(const float4*)(xp + 4);
        float vv[8] = {v0.x, v0.y, v0.z, v0.w, v1.x, v1.y, v1.z, v1.w};
        union { bf16x8 v; unsigned short u[8]; } ahi, alo;
#pragma unroll
        for (int j = 0; j < 8; ++j) {
            unsigned short hi = bf_hi_trunc(vv[j]);
            ahi.u[j] = hi;
            alo.u[j] = f2bf_rne(vv[j] - bf_to_f(hi));
        }
#pragma unroll
        for (int nt = 0; nt < 8; ++nt) {
            size_t woff = (size_t)(nt * 16 + r16) * IN_DIM + k0;
            bf16x8 bhi = *(const bf16x8*)(Wt_hi + woff);
            bf16x8 blo = *(const bf16x8*)(Wt_lo + woff);
            acc[nt] = __builtin_amdgcn_mfma_f32_16x16x32_bf16(ahi.v, bhi, acc[nt], 0, 0, 0);
            acc[nt] = __builtin_amdgcn_mfma_f32_16x16x32_bf16(alo.v, bhi, acc[nt], 0, 0, 0);
            acc[nt] = __builtin_amdgcn_mfma_f32_16x16x32_bf16(ahi.v, blo, acc[nt], 0, 0, 0);
        }
    }
    float dr[4];
#pragma unroll
    for (int r = 0; r < 4; ++r) dr[r] = dinv[m0 + quad * 4 + r];
#pragma unroll
    for (int nt = 0; nt < 8; ++nt) {
#pragma unroll
        for (int r = 0; r < 4; ++r) {
            int row = m0 + quad * 4 + r;
            int col = nt * 16 + r16;
            hs[(size_t)row * OUT_DIM + col] = f2bf_rne(acc[nt][r] * dr[r]);
        }
    }
}

// Cursor atomics hit the SAME replica as k_count (identical grid + blockIdx&7),
// so segment accounting is exact and atomic lines stay XCD-local.
__global__ __launch_bounds__(256) void
k_fill(const int* __restrict__ edge, int* __restrict__ fill_x,
       unsigned short* __restrict__ csr) {
    int e4 = blockIdx.x * 256 + threadIdx.x;
    int* my = fill_x + (blockIdx.x & (NREP - 1)) * N_NODES;
    if (e4 < N_EDGES / 4) {
        int4 s = ((const int4*)edge)[e4];
        int4 d = ((const int4*)(edge + N_EDGES))[e4];
        int p;
        p = atomicAdd(&my[d.x], 1); csr[p] = (unsigned short)s.x;
        p = atomicAdd(&my[d.y], 1); csr[p] = (unsigned short)s.y;
        p = atomicAdd(&my[d.z], 1); csr[p] = (unsigned short)s.z;
        p = atomicAdd(&my[d.w], 1); csr[p] = (unsigned short)s.w;
    }
}

// One wave per node. Lanes 0-31 even-indexed edges, lanes 32-63 odd; each lane
// gathers uint2 (4 dims) so one VMEM covers TWO edges' 256B rows. csr consumed
// as uniform dwords. Halves merged via shfl(lane^32).
__global__ __launch_bounds__(256) void
k_agg_snn(const unsigned short* __restrict__ hs,
          const int* __restrict__ offs, const int* __restrict__ deg,
          const float* __restrict__ dinv,
          const unsigned short* __restrict__ csr,
          float* __restrict__ out) {
    int node = blockIdx.x * 4 + (threadIdx.x >> 6);   // one wave per node
    int lane = threadIdx.x & 63;
    bool hi  = (lane >= 32);
    int  loff = (lane & 31) * 8;                      // byte offset in 256B row
    const char* hsb = (const char*)hs;

    uint2 qs = *(const uint2*)(hsb + (size_t)node * 256 + loff);
    float a0 = hi ? bf_lo(qs.x) : 0.f;
    float a1 = hi ? bf_hi(qs.x) : 0.f;
    float a2 = hi ? bf_lo(qs.y) : 0.f;
    float a3 = hi ? bf_hi(qs.y) : 0.f;

    int beg = __builtin_amdgcn_readfirstlane(offs[node]);
    int end = __builtin_amdgcn_readfirstlane(offs[node] + deg[node]);

    int j = beg;
    if (j & 1) {                                      // align to even element
        unsigned s = csr[j];
        if (!hi) {
            uint2 q = *(const uint2*)(hsb + (size_t)s * 256 + loff);
            a0 += bf_lo(q.x); a1 += bf_hi(q.x);
            a2 += bf_lo(q.y); a3 += bf_hi(q.y);
        }
        ++j;
    }
    int nd = (end - j) >> 1;                          // edge pairs
    const unsigned* cw = (const unsigned*)(csr + j);  // dword-aligned now
    int k = 0;
    for (; k + 8 <= nd; k += 8) {                     // 16 edges in flight
        unsigned d[8];
#pragma unroll
        for (int q = 0; q < 8; ++q) d[q] = cw[k + q];
        uint2 g[8];
#pragma unroll
        for (int q = 0; q < 8; ++q) {
            unsigned s = hi ? (d[q] >> 16) : (d[q] & 0xffffu);
            g[q] = *(const uint2*)(hsb + (size_t)s * 256 + loff);
        }
#pragma unroll
        for (int q = 0; q < 8; ++q) {
            a0 += bf_lo(g[q].x); a1 += bf_hi(g[q].x);
            a2 += bf_lo(g[q].y); a3 += bf_hi(g[q].y);
        }
    }
    for (; k < nd; ++k) {
        unsigned d = cw[k];
        unsigned s = hi ? (d >> 16) : (d & 0xffffu);
        uint2 q = *(const uint2*)(hsb + (size_t)s * 256 + loff);
        a0 += bf_lo(q.x); a1 += bf_hi(q.x);
        a2 += bf_lo(q.y); a3 += bf_hi(q.y);
    }
    int jt = j + 2 * nd;
    if (jt < end) {                                   // odd tail edge
        unsigned s = csr[jt];
        if (!hi) {
            uint2 q = *(const uint2*)(hsb + (size_t)s * 256 + loff);
            a0 += bf_lo(q.x); a1 += bf_hi(q.x);
            a2 += bf_lo(q.y); a3 += bf_hi(q.y);
        }
    }

    a0 += __shfl(a0, lane ^ 32);
    a1 += __shfl(a1, lane ^ 32);
    a2 += __shfl(a2, lane ^ 32);
    a3 += __shfl(a3, lane ^ 32);

    float di = dinv[node];
    float u0 = a0 * di * 0.1f, u1 = a1 * di * 0.1f;   // STEP_SIZE
    float u2 = a2 * di * 0.1f, u3 = a3 * di * 0.1f;
    float z0 = 0.f, z1 = 0.f, z2 = 0.f, z3 = 0.f;

    const size_t plane = (size_t)N_NODES * 128;       // floats per t-plane
    size_t base = (size_t)node * 128 + (size_t)(lane & 31) * 4
                + (hi ? (size_t)T_STEPS * plane : 0);
#pragma unroll
    for (int t = 0; t < T_STEPS; ++t) {
        float H0 = z0 + (u0 - z0) * 0.5f;             // TAU = 2
        float H1 = z1 + (u1 - z1) * 0.5f;
        float H2 = z2 + (u2 - z2) * 0.5f;
        float H3 = z3 + (u3 - z3) * 0.5f;
        float o0 = (H0 >= 1.0f) ? 1.0f : 0.0f;        // V_THRESHOLD = 1
        float o1 = (H1 >= 1.0f) ? 1.0f : 0.0f;
        float o2 = (H2 >= 1.0f) ? 1.0f : 0.0f;
        float o3 = (H3 >= 1.0f) ? 1.0f : 0.0f;
        z0 = H0 - o0; z1 = H1 - o1; z2 = H2 - o2; z3 = H3 - o3;
        f32x4 v = {hi ? z0 : o0, hi ? z1 : o1,
                   hi ? z2 : o2, hi ? z3 : o3};
        __builtin_nontemporal_store(v, (f32x4*)(out + base + (size_t)t * plane));
    }
}

extern "C" void kernel_launch(void* const* d_in, const int* in_sizes, int n_in,
                              void* d_out, int out_size, void* d_ws, size_t ws_size,
                              hipStream_t stream) {
    const float* x  = (const float*)d_in[0];
    const float* W  = (const float*)d_in[1];
    const int*   ei = (const int*)d_in[2];
    float* out = (float*)d_out;

    char* ws = (char*)d_ws;
    unsigned short* hs     = (unsigned short*)(ws + 0);
    unsigned short* Wt_hi  = (unsigned short*)(ws + 12800000);
    unsigned short* Wt_lo  = (unsigned short*)(ws + 12865536);
    int*            cnt_x  = (int*)(ws + 12931072);
    int*            fill_x = (int*)(ws + 14531072);
    int*            offs   = (int*)(ws + 16131072);
    int*            deg    = (int*)(ws + 16331072);
    float*          dinv   = (float*)(ws + 16531072);
    int*            part   = (int*)(ws + 16731072);
    unsigned short* csr    = (unsigned short*)(ws + 16731328);

    hipMemsetAsync(cnt_x, 0, 1600000, stream);

    k_count<<<1563, 256, 0, stream>>>(W, Wt_hi, Wt_lo, ei, cnt_x);
    k_scanA<<<49, 256, 0, stream>>>(cnt_x, part);
    k_scanB<<<1, 64, 0, stream>>>(part);
    k_scanC<<<49, 256, 0, stream>>>(cnt_x, part, offs, deg, fill_x, dinv);
    k_gemm<<<782, 256, 0, stream>>>(x, Wt_hi, Wt_lo, dinv, hs);
    k_fill<<<1563, 256, 0, stream>>>(ei, fill_x, csr);
    k_agg_snn<<<12500, 256, 0, stream>>>(hs, offs, deg, dinv, csr, out);
}

// Round 5
// 693.635 us; speedup vs baseline: 1.0220x; 1.0010x over previous
//
#include <hip/hip_runtime.h>
#include <hip/hip_bf16.h>

#define N_NODES 50000
#define N_EDGES 1600000
#define IN_DIM  256
#define OUT_DIM 128
#define T_STEPS 8
#define NREP    8          // counter replicas (≈ one per XCD)

typedef __attribute__((ext_vector_type(8))) short bf16x8;
typedef __attribute__((ext_vector_type(4))) float f32x4;
typedef __attribute__((ext_vector_type(2))) float f32x2;

// ---- ws layout (bytes) ----
// hs_s   : bf16 [4][N][32]  @ 0           (12,800,000)  slice-major: slice s holds dims [32s,32s+32)
// Wt_hi  : bf16 [128*256]   @ 12,800,000  (65,536)
// Wt_lo  : bf16 [128*256]   @ 12,865,536  (65,536)
// cnt_x  : int  [8][N]      @ 12,931,072  (1,600,000)  (memset to 0)
// fill_x : int  [8][N]      @ 14,531,072  (1,600,000)
// offs   : int  [N]         @ 16,131,072  (200,000)
// deg    : int  [N]         @ 16,331,072  (200,000)
// dinv   : f32  [N]         @ 16,531,072  (200,000)
// part   : int  [64]        @ 16,731,072  (256)
// csr    : u16  [E]         @ 16,731,328  (3,200,000)

__device__ inline unsigned short bf_hi_trunc(float x) {
    return (unsigned short)(__float_as_uint(x) >> 16);
}
__device__ inline float bf_to_f(unsigned short u) {
    return __uint_as_float((unsigned)u << 16);
}
__device__ inline unsigned short f2bf_rne(float a) {
    __hip_bfloat16 t = __float2bfloat16(a);
    return *(unsigned short*)&t;
}
__device__ inline float bf_lo(unsigned p) { return __uint_as_float(p << 16); }
__device__ inline float bf_hi(unsigned p) { return __uint_as_float(p & 0xffff0000u); }

// W split (hi/lo bf16, transposed) + replicated dst histogram.
__global__ __launch_bounds__(256) void
k_count(const float* __restrict__ W,
        unsigned short* __restrict__ Wt_hi,
        unsigned short* __restrict__ Wt_lo,
        const int* __restrict__ edge, int* __restrict__ cnt_x) {
    int idx = blockIdx.x * 256 + threadIdx.x;
    int* my = cnt_x + (blockIdx.x & (NREP - 1)) * N_NODES;
    if (idx < N_EDGES / 4) {
        int4 d = ((const int4*)(edge + N_EDGES))[idx];
        atomicAdd(&my[d.x], 1);
        atomicAdd(&my[d.y], 1);
        atomicAdd(&my[d.z], 1);
        atomicAdd(&my[d.w], 1);
    }
    if (idx < 32768) {
        int n = idx >> 8;      // out dim
        int k = idx & 255;     // in dim
        float w = W[k * OUT_DIM + n];
        unsigned short hi = bf_hi_trunc(w);
        Wt_hi[idx] = hi;
        Wt_lo[idx] = f2bf_rne(w - bf_to_f(hi));
    }
}

// ---- 3-phase exclusive scan over per-node totals (sum of 8 replicas) ----
__global__ __launch_bounds__(256) void
k_scanA(const int* __restrict__ cnt_x, int* __restrict__ part) {
    int t = threadIdx.x;
    int i4 = blockIdx.x * 256 + t;
    int4 v = make_int4(0, 0, 0, 0);
    if (i4 < 12500) {
#pragma unroll
        for (int r = 0; r < NREP; ++r) {
            int4 c = ((const int4*)(cnt_x + r * N_NODES))[i4];
            v.x += c.x; v.y += c.y; v.z += c.z; v.w += c.w;
        }
    }
    int s = v.x + v.y + v.z + v.w;
    __shared__ int sd[256];
    sd[t] = s; __syncthreads();
    for (int o = 128; o > 0; o >>= 1) {
        if (t < o) sd[t] += sd[t + o];
        __syncthreads();
    }
    if (t == 0) part[blockIdx.x] = sd[0];
}

__global__ void k_scanB(int* __restrict__ part) {   // 1 wave
    int l = threadIdx.x;
    int v = (l < 49) ? part[l] : 0;
    int orig = v;
    for (int o = 1; o < 64; o <<= 1) {
        int u = __shfl_up(v, o);
        if (l >= o) v += u;
    }
    if (l < 49) part[l] = v - orig;   // exclusive
}

// offs/deg/dinv + the 8 per-node replica segment cursors.
__global__ __launch_bounds__(256) void
k_scanC(const int* __restrict__ cnt_x, const int* __restrict__ part,
        int* __restrict__ offs, int* __restrict__ deg,
        int* __restrict__ fill_x, float* __restrict__ dinv) {
    int t = threadIdx.x;
    int i4 = blockIdx.x * 256 + t;
    int4 vr[NREP];
    int4 tot = make_int4(0, 0, 0, 0);
    if (i4 < 12500) {
#pragma unroll
        for (int r = 0; r < NREP; ++r) {
            vr[r] = ((const int4*)(cnt_x + r * N_NODES))[i4];
            tot.x += vr[r].x; tot.y += vr[r].y;
            tot.z += vr[r].z; tot.w += vr[r].w;
        }
    } else {
#pragma unroll
        for (int r = 0; r < NREP; ++r) vr[r] = make_int4(0, 0, 0, 0);
    }
    int s = tot.x + tot.y + tot.z + tot.w;
    __shared__ int sd[256];
    sd[t] = s; __syncthreads();
    for (int o = 1; o < 256; o <<= 1) {           // inclusive Hillis-Steele
        int u = (t >= o) ? sd[t - o] : 0;
        __syncthreads();
        sd[t] += u;
        __syncthreads();
    }
    if (i4 < 12500) {
        int base = part[blockIdx.x] + sd[t] - s;  // exclusive
        int4 o4;
        o4.x = base;
        o4.y = o4.x + tot.x;
        o4.z = o4.y + tot.y;
        o4.w = o4.z + tot.z;
        ((int4*)offs)[i4] = o4;
        ((int4*)deg)[i4]  = tot;
        float4 d4;
        d4.x = rsqrtf((float)(tot.x + 1));
        d4.y = rsqrtf((float)(tot.y + 1));
        d4.z = rsqrtf((float)(tot.z + 1));
        d4.w = rsqrtf((float)(tot.w + 1));
        ((float4*)dinv)[i4] = d4;
        int c0 = o4.x, c1 = o4.y, c2 = o4.z, c3 = o4.w;
#pragma unroll
        for (int r = 0; r < NREP; ++r) {
            ((int4*)(fill_x + r * N_NODES))[i4] = make_int4(c0, c1, c2, c3);
            c0 += vr[r].x; c1 += vr[r].y; c2 += vr[r].z; c3 += vr[r].w;
        }
    }
}

// Fused GEMM (blocks 0..781) + CSR fill (blocks 782..2344). Both depend only
// on scanC; no inter-block communication, so plain same-kernel fusion is safe.
__global__ __launch_bounds__(256) void
k_gf(const float* __restrict__ x,
     const unsigned short* __restrict__ Wt_hi,
     const unsigned short* __restrict__ Wt_lo,
     const float* __restrict__ dinv,
     unsigned short* __restrict__ hs,
     const int* __restrict__ edge, int* __restrict__ fill_x,
     unsigned short* __restrict__ csr) {
    if (blockIdx.x < 782) {
        int wave = blockIdx.x * 4 + (threadIdx.x >> 6);
        if (wave >= N_NODES / 16) return;       // 3125 M-tiles of 16 rows
        int lane = threadIdx.x & 63;
        int quad = lane >> 4;
        int r16  = lane & 15;
        int m0 = wave * 16;

        f32x4 acc[8];
#pragma unroll
        for (int nt = 0; nt < 8; ++nt) acc[nt] = (f32x4){0.f, 0.f, 0.f, 0.f};
#pragma unroll
        for (int kt = 0; kt < 8; ++kt) {
            int k0 = kt * 32 + quad * 8;
            const float* xp = x + (size_t)(m0 + r16) * IN_DIM + k0;
            float4 v0 = *(const float4*)xp;
            float4 v1 = *(const float4*)(xp + 4);
            float vv[8] = {v0.x, v0.y, v0.z, v0.w, v1.x, v1.y, v1.z, v1.w};
            union { bf16x8 v; unsigned short u[8]; } ahi, alo;
#pragma unroll
            for (int j = 0; j < 8; ++j) {
                unsigned short hi = bf_hi_trunc(vv[j]);
                ahi.u[j] = hi;
                alo.u[j] = f2bf_rne(vv[j] - bf_to_f(hi));
            }
#pragma unroll
            for (int nt = 0; nt < 8; ++nt) {
                size_t woff = (size_t)(nt * 16 + r16) * IN_DIM + k0;
                bf16x8 bhi = *(const bf16x8*)(Wt_hi + woff);
                bf16x8 blo = *(const bf16x8*)(Wt_lo + woff);
                acc[nt] = __builtin_amdgcn_mfma_f32_16x16x32_bf16(ahi.v, bhi, acc[nt], 0, 0, 0);
                acc[nt] = __builtin_amdgcn_mfma_f32_16x16x32_bf16(alo.v, bhi, acc[nt], 0, 0, 0);
                acc[nt] = __builtin_amdgcn_mfma_f32_16x16x32_bf16(ahi.v, blo, acc[nt], 0, 0, 0);
            }
        }
        float dr[4];
#pragma unroll
        for (int r = 0; r < 4; ++r) dr[r] = dinv[m0 + quad * 4 + r];
        // slice-major epilogue: hs_s[col>>5][row][col&31]
#pragma unroll
        for (int nt = 0; nt < 8; ++nt) {
#pragma unroll
            for (int r = 0; r < 4; ++r) {
                int row = m0 + quad * 4 + r;
                int col = nt * 16 + r16;
                hs[(size_t)(col >> 5) * (N_NODES * 32) + (size_t)row * 32 + (col & 31)]
                    = f2bf_rne(acc[nt][r] * dr[r]);
            }
        }
    } else {
        int fblk = blockIdx.x - 782;                    // 0..1562, matches k_count grid
        int e4 = fblk * 256 + threadIdx.x;
        int* my = fill_x + (fblk & (NREP - 1)) * N_NODES;
        if (e4 < N_EDGES / 4) {
            int4 s = ((const int4*)edge)[e4];
            int4 d = ((const int4*)(edge + N_EDGES))[e4];
            int p;
            p = atomicAdd(&my[d.x], 1); csr[p] = (unsigned short)s.x;
            p = atomicAdd(&my[d.y], 1); csr[p] = (unsigned short)s.y;
            p = atomicAdd(&my[d.z], 1); csr[p] = (unsigned short)s.z;
            p = atomicAdd(&my[d.w], 1); csr[p] = (unsigned short)s.w;
        }
    }
}

// Dim-sliced aggregate + SNN: 4 passes (pass = blockIdx/12500), each gathers
// from a 3.2 MB slice table that fits a 4 MiB XCD L2. One wave per node per
// pass; lane = 16*e + dl: e picks 1 of 4 edges per csr uint2, dl picks the
// dword (2 dims) in the 64B slice row -> one VMEM per 4 edges.
__global__ __launch_bounds__(256) void
k_agg_snn(const char* __restrict__ hs_s,
          const int* __restrict__ offs, const int* __restrict__ deg,
          const float* __restrict__ dinv,
          const unsigned short* __restrict__ csr,
          float* __restrict__ out) {
    int pass = blockIdx.x / 12500;
    int node = (blockIdx.x % 12500) * 4 + (threadIdx.x >> 6);
    int lane = threadIdx.x & 63;
    int e    = lane >> 4;                 // edge subgroup 0..3
    int dl   = lane & 15;                 // dword within 64B slice row
    const char* base = hs_s + (size_t)pass * 3200000;

    float a0 = 0.f, a1 = 0.f;
    if (e == 0) {                         // self-loop term, counted once
        unsigned q = *(const unsigned*)(base + (size_t)node * 64 + dl * 4);
        a0 += bf_lo(q); a1 += bf_hi(q);
    }

    int beg = __builtin_amdgcn_readfirstlane(offs[node]);
    int end = __builtin_amdgcn_readfirstlane(offs[node] + deg[node]);

    int j = beg;
    while ((j & 3) && j < end) {          // align to edge-quad boundary
        unsigned s = csr[j];
        if (e == 0) {
            unsigned q = *(const unsigned*)(base + (size_t)s * 64 + dl * 4);
            a0 += bf_lo(q); a1 += bf_hi(q);
        }
        ++j;
    }
    int nq = (end - j) >> 2;              // edge quads
    const uint2* cq = (const uint2*)(csr + j);   // 8B-aligned (j%4==0)
    int k = 0;
    for (; k + 8 <= nq; k += 8) {         // 32 edges, 8 gathers in flight
        uint2 d[8];
#pragma unroll
        for (int q = 0; q < 8; ++q) d[q] = cq[k + q];
        unsigned g[8];
#pragma unroll
        for (int q = 0; q < 8; ++q) {
            unsigned w = (e & 2) ? d[q].y : d[q].x;
            unsigned s = (e & 1) ? (w >> 16) : (w & 0xffffu);
            g[q] = *(const unsigned*)(base + (size_t)s * 64 + dl * 4);
        }
#pragma unroll
        for (int q = 0; q < 8; ++q) {
            a0 += bf_lo(g[q]); a1 += bf_hi(g[q]);
        }
    }
    for (; k < nq; ++k) {
        uint2 d = cq[k];
        unsigned w = (e & 2) ? d.y : d.x;
        unsigned s = (e & 1) ? (w >> 16) : (w & 0xffffu);
        unsigned q = *(const unsigned*)(base + (size_t)s * 64 + dl * 4);
        a0 += bf_lo(q); a1 += bf_hi(q);
    }
    for (int jt = j + 4 * nq; jt < end; ++jt) {   // tail edges (<=3)
        unsigned s = csr[jt];
        if (e == 0) {
            unsigned q = *(const unsigned*)(base + (size_t)s * 64 + dl * 4);
            a0 += bf_lo(q); a1 += bf_hi(q);
        }
    }

    // butterfly across the 4 edge subgroups (same dims, different edges)
    a0 += __shfl(a0, lane ^ 16);
    a1 += __shfl(a1, lane ^ 16);
    a0 += __shfl(a0, lane ^ 32);
    a1 += __shfl(a1, lane ^ 32);

    float di = dinv[node];
    float u0 = a0 * di * 0.1f, u1 = a1 * di * 0.1f;   // STEP_SIZE
    float z0 = 0.f, z1 = 0.f;

    const size_t plane = (size_t)N_NODES * 128;       // floats per t-plane
    size_t ob = (size_t)node * 128 + pass * 32 + 2 * dl;
#pragma unroll
    for (int t = 0; t < T_STEPS; ++t) {
        float H0 = z0 + (u0 - z0) * 0.5f;             // TAU = 2
        float H1 = z1 + (u1 - z1) * 0.5f;
        float o0 = (H0 >= 1.0f) ? 1.0f : 0.0f;        // V_THRESHOLD = 1
        float o1 = (H1 >= 1.0f) ? 1.0f : 0.0f;
        z0 = H0 - o0;
        z1 = H1 - o1;
        if (e == 0) {
            f32x2 v = {o0, o1};
            __builtin_nontemporal_store(v, (f32x2*)(out + (size_t)t * plane + ob));
        }
        if (e == 1) {
            f32x2 v = {z0, z1};
            __builtin_nontemporal_store(v, (f32x2*)(out + (size_t)(T_STEPS + t) * plane + ob));
        }
    }
}

extern "C" void kernel_launch(void* const* d_in, const int* in_sizes, int n_in,
                              void* d_out, int out_size, void* d_ws, size_t ws_size,
                              hipStream_t stream) {
    const float* x  = (const float*)d_in[0];
    const float* W  = (const float*)d_in[1];
    const int*   ei = (const int*)d_in[2];
    float* out = (float*)d_out;

    char* ws = (char*)d_ws;
    unsigned short* hs     = (unsigned short*)(ws + 0);
    unsigned short* Wt_hi  = (unsigned short*)(ws + 12800000);
    unsigned short* Wt_lo  = (unsigned short*)(ws + 12865536);
    int*            cnt_x  = (int*)(ws + 12931072);
    int*            fill_x = (int*)(ws + 14531072);
    int*            offs   = (int*)(ws + 16131072);
    int*            deg    = (int*)(ws + 16331072);
    float*          dinv   = (float*)(ws + 16531072);
    int*            part   = (int*)(ws + 16731072);
    unsigned short* csr    = (unsigned short*)(ws + 16731328);

    (void)hipMemsetAsync(cnt_x, 0, 1600000, stream);

    k_count<<<1563, 256, 0, stream>>>(W, Wt_hi, Wt_lo, ei, cnt_x);
    k_scanA<<<49, 256, 0, stream>>>(cnt_x, part);
    k_scanB<<<1, 64, 0, stream>>>(part);
    k_scanC<<<49, 256, 0, stream>>>(cnt_x, part, offs, deg, fill_x, dinv);
    k_gf<<<2345, 256, 0, stream>>>(x, Wt_hi, Wt_lo, dinv, hs, ei, fill_x, csr);
    k_agg_snn<<<50000, 256, 0, stream>>>((const char*)hs, offs, deg, dinv, csr, out);
}